// Round 5
// baseline (460.998 us; speedup 1.0000x reference)
//
#include <hip/hip_runtime.h>
#include <math.h>
#include <stdint.h>
#include <stddef.h>

// ---------- types ----------
typedef short bf16x8 __attribute__((ext_vector_type(8)));   // 8 bf16 (4 VGPRs)
typedef short bf16x4 __attribute__((ext_vector_type(4)));   // 4 bf16 (2 VGPRs)
typedef float f32x4  __attribute__((ext_vector_type(4)));

// problem constants
#define BATCH   8
#define D       1024          // model dim == GEMM K == N (clean 1024 after FFW fold)
#define POSD    32
#define WIN     1056          // W row length (D + POSD)
#define MBARS   2048
#define MROWS   16384         // BATCH * MBARS
#define NOUT    1024

// fp32 -> bf16 round-to-nearest-even
__device__ __forceinline__ short f2bf(float f) {
    unsigned u = __builtin_bit_cast(unsigned, f);
    u += 0x7fffu + ((u >> 16) & 1u);
    return (short)(u >> 16);
}

// async global -> LDS, 16B/lane; LDS dest = wave-uniform base + lane*16
__device__ __forceinline__ void async_load16(const short* g, short* l) {
    __builtin_amdgcn_global_load_lds((__attribute__((address_space(1))) void*)g,
                                     (__attribute__((address_space(3))) void*)l,
                                     16, 0, 0);
}

// raw workgroup barrier with compiler-level memory fence, NO vmcnt/lgkmcnt drain
__device__ __forceinline__ void bar() {
    asm volatile("" ::: "memory");
    __builtin_amdgcn_s_barrier();
    asm volatile("" ::: "memory");
}

// ---------- kernel 1: prep (unchanged, verified round 4) ----------
// blocks [0, MROWS):           segment mean (K=4) -> h bf16 [MROWS][1024]
// blocks [MROWS, MROWS+1024):  cast W[:, :1024] -> Wb bf16 [1024][1024]
// blocks [MROWS+1024, +256):   FFW[mb][n] = bias[n] + sum_j ff[mb][j]*W[n][1024+j]
__global__ __launch_bounds__(256) void prep3(const float* __restrict__ x,
                                             const float* __restrict__ W,
                                             const float* __restrict__ bias,
                                             short* __restrict__ h,
                                             short* __restrict__ Wb,
                                             float* __restrict__ FFW) {
    const int t   = threadIdx.x;
    const int bid = blockIdx.x;
    if (bid < MROWS) {
        const float4* src = (const float4*)(x + (size_t)bid * 4096);
        float4 s0 = src[t], s1 = src[t + 256], s2 = src[t + 512], s3 = src[t + 768];
        bf16x4 o = { f2bf((s0.x + s1.x + s2.x + s3.x) * 0.25f),
                     f2bf((s0.y + s1.y + s2.y + s3.y) * 0.25f),
                     f2bf((s0.z + s1.z + s2.z + s3.z) * 0.25f),
                     f2bf((s0.w + s1.w + s2.w + s3.w) * 0.25f) };
        *(bf16x4*)(h + (size_t)bid * D + t * 4) = o;
    } else if (bid < MROWS + NOUT) {
        const int rw = bid - MROWS;
        float4 v = ((const float4*)(W + (size_t)rw * WIN))[t];   // cols 0..1023
        bf16x4 o = { f2bf(v.x), f2bf(v.y), f2bf(v.z), f2bf(v.w) };
        *(bf16x4*)(Wb + (size_t)rw * D + t * 4) = o;
    } else {
        const int mb0 = (bid - MROWS - NOUT) * 8;                // 8 bar rows per block
        __shared__ float ff[8][32];
        if (t < 32) {
            float fr = expf((float)(t & 15) * (6.907755278982137f / 15.0f)); // linspace(0,ln1000,16)
#pragma unroll
            for (int e = 0; e < 8; ++e) {
                float pos = (float)(mb0 + e) * (1.0f / (float)(MBARS - 1));
                float ang = pos * fr;
                ff[e][t] = (t < 16) ? sinf(ang) : cosf(ang);
            }
        }
        __syncthreads();
#pragma unroll
        for (int u = 0; u < 4; ++u) {
            const int n = t + u * 256;
            const float* wp = W + (size_t)n * WIN + D;
            float4 wv[8];
#pragma unroll
            for (int blk = 0; blk < 8; ++blk) wv[blk] = ((const float4*)wp)[blk];
            const float bn = bias[n];
#pragma unroll
            for (int e = 0; e < 8; ++e) {
                float s = bn;
#pragma unroll
                for (int blk = 0; blk < 8; ++blk) {
                    s += ff[e][blk * 4 + 0] * wv[blk].x + ff[e][blk * 4 + 1] * wv[blk].y
                       + ff[e][blk * 4 + 2] * wv[blk].z + ff[e][blk * 4 + 3] * wv[blk].w;
                }
                FFW[(size_t)(mb0 + e) * NOUT + n] = s;
            }
        }
    }
}

// ---------- kernel 2: C[16384,1024] = h @ Wb^T + FFW  (v5) ----------
// 128x128 tile, 256 threads, 2x2 waves.  Changes vs round-4 (m97-style):
//  * B never staged to LDS: per-lane bf16x8 fragment loads straight from L2-resident Wb
//    (zero cross-wave sharing existed; saves 16 KB LDS + half the staged bytes).
//  * A double-buffered (2 x 16 KB): stage(k+1) issued at TOP of iter k, then counted
//    s_waitcnt vmcnt(4) (allow only the 4 just-issued loads in flight) + raw s_barrier —
//    no vmcnt(0) drain in the main loop (the m97 ~20% stall).  End-of-iter raw barrier
//    gives slot safety: all waves' ds_reads of buf^1 precede the overwriting stage issue.
//  * vmcnt in-order retirement => vmcnt(4) forces stage(k) + prior b-loads complete.
__global__ __launch_bounds__(256, 3) void gemm_bt(const short* __restrict__ A,   // h  [MROWS, D]
                                                  const short* __restrict__ B,   // Wb [NOUT, D]
                                                  const float* __restrict__ FFW, // [MBARS, NOUT]
                                                  float* __restrict__ C) {
    __shared__ short As[2 * 128 * 64];   // 2 x 16 KB, swizzled row-major [m][k]

    const int tid  = threadIdx.x;
    const int wave = tid >> 6;
    const int lane = tid & 63;
    const int wrow = wave >> 1;          // 2x2 wave grid -> 64x64 per wave
    const int wcol = wave & 1;

    const int m0 = blockIdx.x * 128;     // gridDim.x = 128
    const int n0 = blockIdx.y * 128;     // gridDim.y = 8

    // A staging: issue i covers rows [i*32, i*32+32); thread t -> row t>>3, octet (t&7)^swz.
    // Slot j of row r holds global octet j^(r&7) (pre-swizzled SOURCE; LDS dest linear).
    const int r8   = tid >> 3;                    // 0..31
    const int soct = (tid & 7) ^ (r8 & 7);
    const short* ag = A + (size_t)(m0 + r8) * D + soct * 8;
    const int    al = wave * 512;                 // per-wave LDS chunk (shorts); +i*2048 per issue

    // fragment decode
    const int r  = lane & 15;
    const int q  = lane >> 4;                     // k-octet within 32-wide step
    const int rx = r & 7;
    const int ab = (wrow * 64 + r) * 64;          // A frag row base (within buffer)
    const int sl0 = ((q    ) ^ rx) * 8;           // s=0: k-octets 0..3
    const int sl1 = ((4 + q) ^ rx) * 8;           // s=1: k-octets 4..7

    // B fragment base: n = n0 + wcol*64 + j*16 + r, k-octet q (linear Wb)
    const short* bgl = B + (size_t)(n0 + wcol * 64 + r) * D + q * 8;

    f32x4 acc[4][4] = {};

    // prologue: issue stage of K-tile 0 into buf 0 (completion enforced by iter-0 wait+bar)
#pragma unroll
    for (int i = 0; i < 4; ++i)
        async_load16(ag + (size_t)i * 32 * D, As + al + i * 2048);

    for (int k0 = 0; k0 < 16; ++k0) {
        // issue stage of K-tile k0+1 into the other buffer (slot-safe: reads of that
        // buffer finished before last iter's end barrier)
        if (k0 < 15) {
            const short* agk = ag + (k0 + 1) * 64;
            short* nb = As + (((k0 + 1) & 1) << 13) + al;
#pragma unroll
            for (int i = 0; i < 4; ++i)
                async_load16(agk + (size_t)i * 32 * D, nb + i * 2048);
        }
        // counted wait: allow the 4 just-issued loads; forces stage(k0) (older) complete
        if (k0 < 15) asm volatile("s_waitcnt vmcnt(4)" ::: "memory");
        else         asm volatile("s_waitcnt vmcnt(0)" ::: "memory");
        bar();   // now ALL waves' stage(k0) loads have landed

        const short* ap = As + ((k0 & 1) << 13) + ab;
        const int kc = k0 * 64;
#pragma unroll
        for (int s = 0; s < 2; ++s) {
            const int sl = s ? sl1 : sl0;
            bf16x8 a[4], b[4];
#pragma unroll
            for (int i = 0; i < 4; ++i) a[i] = *(const bf16x8*)(ap + i * 1024 + sl);
#pragma unroll
            for (int j = 0; j < 4; ++j) b[j] = *(const bf16x8*)(bgl + (size_t)j * 16 * D + kc + s * 32);
#pragma unroll
            for (int i = 0; i < 4; ++i)
#pragma unroll
                for (int j = 0; j < 4; ++j)
                    acc[i][j] = __builtin_amdgcn_mfma_f32_16x16x32_bf16(a[i], b[j], acc[i][j], 0, 0, 0);
        }
        bar();   // all waves done reading buf (k0&1) before next iter overwrites buf^1's twin
    }

    // epilogue: C/D layout col = lane&15, row = (lane>>4)*4 + reg; add FFW[row&2047][col]
    const int rr0 = m0 + wrow * 64 + (q << 2);
    const int c0  = n0 + wcol * 64 + r;
#pragma unroll
    for (int i = 0; i < 4; ++i)
#pragma unroll
        for (int rg = 0; rg < 4; ++rg) {
            const int row = rr0 + i * 16 + rg;
            const float* fw = FFW + (size_t)(row & (MBARS - 1)) * NOUT + c0;
            float* cp = C + (size_t)row * NOUT + c0;
#pragma unroll
            for (int j = 0; j < 4; ++j)
                cp[j * 16] = acc[i][j][rg] + fw[j * 16];
        }
}

extern "C" void kernel_launch(void* const* d_in, const int* in_sizes, int n_in,
                              void* d_out, int out_size, void* d_ws, size_t ws_size,
                              hipStream_t stream) {
    const float* x    = (const float*)d_in[0];   // [8, 8192, 1024]
    const float* W    = (const float*)d_in[1];   // [1024, 1056]
    const float* bias = (const float*)d_in[2];   // [1024]
    float* out = (float*)d_out;                  // [8, 2048, 1024]

    // workspace: Wb bf16 [1024][1024] (2 MB) | FFW f32 [2048][1024] (8 MB) | h bf16 [16384][1024] (32 MB)
    short* Wb  = (short*)d_ws;
    float* FFW = (float*)((char*)d_ws + (size_t)NOUT * D * sizeof(short));
    short* h   = (short*)((char*)FFW + (size_t)MBARS * NOUT * sizeof(float));

    prep3  <<<dim3(MROWS + NOUT + MBARS / 8), dim3(256), 0, stream>>>(x, W, bias, h, Wb, FFW);
    gemm_bt<<<dim3(MROWS / 128, NOUT / 128), dim3(256), 0, stream>>>(h, Wb, FFW, out);
}